// Round 1
// baseline (1214.679 us; speedup 1.0000x reference)
//
#include <hip/hip_runtime.h>
#include <math.h>

// CarryLSTMModel: B=8192, T=1024, D=16, H=16
// Strategy: 16 lanes per batch element; lane u owns hidden unit u
// (gate columns u, u+16, u+32, u+48). Weights held in VGPRs (128 floats/lane).
// Per step: 4x float4 x-load, 128 v_fmac_f32, lane-local gates, 16-shfl h broadcast.

#define BB 8192
#define TT 1024
#define DD 16
#define HH 16

__device__ __forceinline__ float fast_sigmoid(float x) {
    // 1/(1+e^-x); rcp is ~1ulp, fine vs 1.9e-2 threshold
    return __builtin_amdgcn_rcpf(1.0f + __expf(-x));
}
__device__ __forceinline__ float fast_tanh(float x) {
    // tanh = 1 - 2/(e^{2x}+1); saturates correctly at +/-inf
    return 1.0f - 2.0f * __builtin_amdgcn_rcpf(1.0f + __expf(2.0f * x));
}

__global__ __launch_bounds__(256, 2) void carry_lstm_kernel(
    const float* __restrict__ x,    // [B, T, 16]
    const float* __restrict__ Wi,   // [16, 64] row-major, gates (i,f,g,o)
    const float* __restrict__ Wh,   // [16, 64]
    const float* __restrict__ b,    // [64]
    const float* __restrict__ Wd,   // [16, 2]
    const float* __restrict__ bd,   // [2]
    float* __restrict__ out)        // [B, 2] softmax probs
{
    const int tid = blockIdx.x * blockDim.x + threadIdx.x;
    const int e = tid >> 4;        // batch element
    const int u = tid & 15;        // hidden unit owned by this lane

    // ---- load weights into registers: wI[k][g], wH[k][g], g=0..3 -> col g*16+u
    float wI[DD][4], wH[HH][4];
#pragma unroll
    for (int k = 0; k < DD; ++k) {
#pragma unroll
        for (int g = 0; g < 4; ++g) {
            wI[k][g] = Wi[k * 64 + g * 16 + u];
            wH[k][g] = Wh[k * 64 + g * 16 + u];
        }
    }
    float bz[4];
#pragma unroll
    for (int g = 0; g < 4; ++g) bz[g] = b[g * 16 + u];

    const float4* xv = (const float4*)(x + (size_t)e * (TT * DD));

    float c = 0.0f;
    float hb[HH];
#pragma unroll
    for (int k = 0; k < HH; ++k) hb[k] = 0.0f;

    // preload t=0 (4 x float4 = the 16 inputs of this element's timestep)
    float4 xa = xv[0], xb = xv[1], xc = xv[2], xd = xv[3];

    for (int t = 0; t < TT; ++t) {
        // issue next-step loads early (clamped; no branch, no OOB)
        const int tn = (t + 1 < TT) ? (t + 1) : (TT - 1);
        const float4* nxt = xv + tn * 4;
        float4 na = nxt[0], nb = nxt[1], nc = nxt[2], nd = nxt[3];

        const float xin[DD] = {xa.x, xa.y, xa.z, xa.w,
                               xb.x, xb.y, xb.z, xb.w,
                               xc.x, xc.y, xc.z, xc.w,
                               xd.x, xd.y, xd.z, xd.w};

        float z0 = bz[0], z1 = bz[1], z2 = bz[2], z3 = bz[3];
#pragma unroll
        for (int k = 0; k < DD; ++k) {
            z0 = fmaf(xin[k], wI[k][0], z0);
            z1 = fmaf(xin[k], wI[k][1], z1);
            z2 = fmaf(xin[k], wI[k][2], z2);
            z3 = fmaf(xin[k], wI[k][3], z3);
        }
#pragma unroll
        for (int k = 0; k < HH; ++k) {
            z0 = fmaf(hb[k], wH[k][0], z0);
            z1 = fmaf(hb[k], wH[k][1], z1);
            z2 = fmaf(hb[k], wH[k][2], z2);
            z3 = fmaf(hb[k], wH[k][3], z3);
        }

        // gates: z = [i, f, g, o]
        const float ig = fast_sigmoid(z0);
        const float fg = fast_sigmoid(z1);
        const float gg = fast_tanh(z2);
        const float og = fast_sigmoid(z3);
        c = fmaf(fg, c, ig * gg);
        const float h = og * fast_tanh(c);

        // broadcast the 16 new h values within the 16-lane group
#pragma unroll
        for (int k = 0; k < HH; ++k) hb[k] = __shfl(h, k, 16);

        xa = na; xb = nb; xc = nc; xd = nd;
    }

    // ---- head: logits = c_T @ Wd + bd  (cell state!), then softmax over 2
    float p0 = c * Wd[u * 2 + 0];
    float p1 = c * Wd[u * 2 + 1];
#pragma unroll
    for (int off = 8; off >= 1; off >>= 1) {
        p0 += __shfl_xor(p0, off, 16);
        p1 += __shfl_xor(p1, off, 16);
    }
    if (u == 0) {
        const float l0 = p0 + bd[0];
        const float l1 = p1 + bd[1];
        const float m = fmaxf(l0, l1);
        const float e0 = __expf(l0 - m);
        const float e1 = __expf(l1 - m);
        const float inv = __builtin_amdgcn_rcpf(e0 + e1);
        out[e * 2 + 0] = e0 * inv;
        out[e * 2 + 1] = e1 * inv;
    }
}

extern "C" void kernel_launch(void* const* d_in, const int* in_sizes, int n_in,
                              void* d_out, int out_size, void* d_ws, size_t ws_size,
                              hipStream_t stream) {
    const float* x  = (const float*)d_in[0];
    const float* Wi = (const float*)d_in[1];
    const float* Wh = (const float*)d_in[2];
    const float* b  = (const float*)d_in[3];
    const float* Wd = (const float*)d_in[4];
    const float* bd = (const float*)d_in[5];
    float* out = (float*)d_out;

    // 8192 elements * 16 lanes = 131072 threads = 512 blocks of 256
    dim3 grid(BB * 16 / 256);
    dim3 block(256);
    hipLaunchKernelGGL(carry_lstm_kernel, grid, block, 0, stream,
                       x, Wi, Wh, b, Wd, bd, out);
}

// Round 2
// 1181.188 us; speedup vs baseline: 1.0284x; 1.0284x over previous
//
#include <hip/hip_runtime.h>
#include <math.h>
#include <stdint.h>

// CarryLSTMModel: B=8192, T=1024, D=16, H=16.
// MFMA scan: 1 wave = 16-element tile. Per step: 4x mfma_f32_16x16x32_bf16
// (A = [x_t | h] K=32, B = [Wi;Wh] per gate, acc init = bias), activations on
// C-layout (4 cells/lane), h round-trips LDS in bf16, c stays fp32 in regs.

#define BB 8192
#define TT 1024
#define DD 16
#define HH 16

typedef __attribute__((ext_vector_type(8))) short short8;  // 8 bf16 (4 VGPRs)
typedef __attribute__((ext_vector_type(4))) float f32x4;   // MFMA C/D

__device__ __forceinline__ short f2bf(float f) {  // RNE fp32->bf16
    uint32_t u = __builtin_bit_cast(uint32_t, f);
    u += 0x7fffu + ((u >> 16) & 1u);
    return (short)(u >> 16);
}

__global__ __launch_bounds__(64) void carry_lstm_mfma(
    const float* __restrict__ x,    // [B, T, 16]
    const float* __restrict__ Wi,   // [16, 64]
    const float* __restrict__ Wh,   // [16, 64]
    const float* __restrict__ b,    // [64]
    const float* __restrict__ Wd,   // [16, 2]
    const float* __restrict__ bd,   // [2]
    float* __restrict__ out)        // [B, 2]
{
    // LDS: [0,768) x-staging bf16 [m][col] stride 48B; [768,1536) h bf16 same
    __shared__ __align__(16) char smem[1536];
    const int lane = threadIdx.x;   // 0..63
    const int n = lane & 15;        // MFMA col (gate-unit) / staging row m
    const int q = lane >> 4;        // quad
    const int e0 = blockIdx.x * 16;

    // ---- B fragments: B[k=q*8+j][col=g*16+n], k 0..15 = Wi rows, 16..31 = Wh
    short8 Bg[4];
    float bias[4];
#pragma unroll
    for (int g = 0; g < 4; ++g) {
#pragma unroll
        for (int j = 0; j < 8; ++j) {
            const int row = q * 8 + j;
            const float w = (row < 16) ? Wi[row * 64 + g * 16 + n]
                                       : Wh[(row - 16) * 64 + g * 16 + n];
            Bg[g][j] = f2bf(w);
        }
        bias[g] = b[g * 16 + n];
    }

    // ---- staging duty: this lane loads element e0+n, cols q*4..q*4+4
    const float* xg = x + (size_t)(e0 + n) * (TT * DD) + q * 4;
    char* xw = &smem[n * 48 + q * 8];              // 8B (4 bf16) x write
    // A-frag read: q 0/1 -> x cols 0-7/8-15; q 2/3 -> h units 0-7/8-15
    const short8* afp = (const short8*)&smem[(q >> 1) * 768 + n * 48 + (q & 1) * 16];

    // ---- init: zero h rows, stage x_0, prefetch x_1
    *(uint2*)&smem[768 + n * 48 + q * 8] = make_uint2(0u, 0u);
    {
        float4 x0 = *(const float4*)(xg);
        uint32_t lo = (uint16_t)f2bf(x0.x) | ((uint32_t)(uint16_t)f2bf(x0.y) << 16);
        uint32_t hi = (uint16_t)f2bf(x0.z) | ((uint32_t)(uint16_t)f2bf(x0.w) << 16);
        *(uint2*)xw = make_uint2(lo, hi);
    }
    float4 xf = *(const float4*)(xg + DD);  // x_1

    float cr[4] = {0.f, 0.f, 0.f, 0.f};

    for (int t = 0; t < TT; ++t) {
        // A-fragment (x_t | h_{t-1}); DS pipe is in-order within the wave
        short8 af = *afp;
        asm volatile("" ::: "memory");  // keep LDS read before this iter's writes

        f32x4 acc0 = {bias[0], bias[0], bias[0], bias[0]};
        f32x4 acc1 = {bias[1], bias[1], bias[1], bias[1]};
        f32x4 acc2 = {bias[2], bias[2], bias[2], bias[2]};
        f32x4 acc3 = {bias[3], bias[3], bias[3], bias[3]};
        acc0 = __builtin_amdgcn_mfma_f32_16x16x32_bf16(af, Bg[0], acc0, 0, 0, 0);
        acc1 = __builtin_amdgcn_mfma_f32_16x16x32_bf16(af, Bg[1], acc1, 0, 0, 0);
        acc2 = __builtin_amdgcn_mfma_f32_16x16x32_bf16(af, Bg[2], acc2, 0, 0, 0);
        acc3 = __builtin_amdgcn_mfma_f32_16x16x32_bf16(af, Bg[3], acc3, 0, 0, 0);

        // prefetch x_{t+2} (clamped)
        const int t2 = (t + 2 < TT) ? (t + 2) : (TT - 1);
        const float4 xf2 = *(const float4*)(xg + (size_t)t2 * DD);

        // ---- 4 cell updates (element m = q*4+r, unit n)
#pragma unroll
        for (int r = 0; r < 4; ++r) {
            float zi = acc0[r], zf = acc1[r], zg = acc2[r], zo = acc3[r];
            zi = fmaxf(zi, -12.f); zf = fmaxf(zf, -12.f);
            zg = fmaxf(zg, -12.f); zo = fmaxf(zo, -12.f);
            const float ea = __expf(-zi);          // exp(-z_i)
            const float ef = __expf(-zf);
            const float G  = __expf(-2.f * zg);    // tanh(zg)=(1-G)/(1+G)
            const float eo = __expf(-zo);
            // c' = [c(1+ea)(1+G) + (1-G)(1+ef)] / [(1+ea)(1+ef)(1+G)]
            float u = fmaf(cr[r], ea, cr[r]);
            u = fmaf(u, G, u);
            const float s  = 1.f - G;
            const float s2 = fmaf(s, ef, s);
            const float num = u + s2;
            const float den = ((ea + 1.f) * (ef + 1.f));
            const float den3 = fmaf(den, G, den);
            const float cn = num * __builtin_amdgcn_rcpf(den3);
            cr[r] = cn;
            // h = (1-C2) / [(1+C2)(1+eo)],  C2 = exp(-2c')
            const float cc = fmaxf(cn, -12.f);
            const float C2 = __expf(-2.f * cc);
            const float hd = (1.f + C2) * (1.f + eo);
            const float h  = (1.f - C2) * __builtin_amdgcn_rcpf(hd);
            *(short*)&smem[768 + (q * 4 + r) * 48 + n * 2] = f2bf(h);
        }

        // stage x_{t+1} (after this iter's frag read; before next iter's)
        {
            uint32_t lo = (uint16_t)f2bf(xf.x) | ((uint32_t)(uint16_t)f2bf(xf.y) << 16);
            uint32_t hi = (uint16_t)f2bf(xf.z) | ((uint32_t)(uint16_t)f2bf(xf.w) << 16);
            *(uint2*)xw = make_uint2(lo, hi);
        }
        xf = xf2;
        asm volatile("" ::: "memory");  // keep writes before next iter's LDS read
    }

    // ---- head: logits = c_T @ Wd + bd (cell state), softmax over 2
    float p0[4], p1[4];
    const float wd0 = Wd[n * 2 + 0], wd1 = Wd[n * 2 + 1];
#pragma unroll
    for (int r = 0; r < 4; ++r) { p0[r] = cr[r] * wd0; p1[r] = cr[r] * wd1; }
#pragma unroll
    for (int off = 1; off < 16; off <<= 1) {
#pragma unroll
        for (int r = 0; r < 4; ++r) {
            p0[r] += __shfl_xor(p0[r], off, 16);
            p1[r] += __shfl_xor(p1[r], off, 16);
        }
    }
#pragma unroll
    for (int r = 0; r < 4; ++r) {
        if (n == r) {
            const float l0 = p0[r] + bd[0];
            const float l1 = p1[r] + bd[1];
            const float m  = fmaxf(l0, l1);
            const float E0 = __expf(l0 - m), E1 = __expf(l1 - m);
            const float inv = __builtin_amdgcn_rcpf(E0 + E1);
            const size_t e = (size_t)(e0 + q * 4 + r);
            out[e * 2 + 0] = E0 * inv;
            out[e * 2 + 1] = E1 * inv;
        }
    }
}

extern "C" void kernel_launch(void* const* d_in, const int* in_sizes, int n_in,
                              void* d_out, int out_size, void* d_ws, size_t ws_size,
                              hipStream_t stream) {
    const float* x  = (const float*)d_in[0];
    const float* Wi = (const float*)d_in[1];
    const float* Wh = (const float*)d_in[2];
    const float* b  = (const float*)d_in[3];
    const float* Wd = (const float*)d_in[4];
    const float* bd = (const float*)d_in[5];
    float* out = (float*)d_out;

    // 8192 elements / 16 per wave = 512 blocks of one wave
    hipLaunchKernelGGL(carry_lstm_mfma, dim3(BB / 16), dim3(64), 0, stream,
                       x, Wi, Wh, b, Wd, bd, out);
}